// Round 13
// baseline (430.492 us; speedup 1.0000x reference)
//
#include <hip/hip_runtime.h>
#include <hip/hip_bf16.h>

// ---------------------------------------------------------------------------
// GraphSAGE 3-layer + global mean pool, fp32 in/out.
//   layer: agg = mean_{e:dst=n} relu(h[src_e]);  h' = agg@Wl^T + bl + h@Wr^T
// R1: sorted-batch pool -> segment reduction.                 810->537us
// R2: parallel scan + wave64 agg + relu-elision.              537->449us
// R3-R5: bf16 MFMA hi/lo split GEMM (3 MFMAs, fp32-class).    449->387us
// R6: layer-2 linearity swap (gather 40-dim not 128-dim).     387->378us
// R7/R8/R9: structural fusions all REGRESSED, reverted.
// R10: union of proven pieces, 13 dispatches.                 378->360us
// R11: bf16 gather tables (2x fewer gather bytes).            360->337us
// R12: plane-ized GEMM inputs: NEUTRAL (GEMMs weren't staging-bound).
// R13: XCD-quarter gather: 12.8MB table > 4MB per-XCD L2 -> ~31% hit rate,
//     HBM-latency-bound at 2.5 TB/s. Split gather into 4 feature quarters,
//     quarter = blockIdx&3; round-robin XCD mapping (blockIdx%8) pins each
//     3.2MB quarter-table to XCD pair {q,q+4} -> L2-resident, L2-rate served.
//     16 lanes x uint per edge-quarter, 4 edges concurrent, unroll-4.
// ---------------------------------------------------------------------------

#define NODES 50000
#define K_DIM 128
#define N_GRAPHS 128

typedef __attribute__((ext_vector_type(8))) short short8;
typedef __attribute__((ext_vector_type(4))) short short4v;
typedef __attribute__((ext_vector_type(4))) float f32x4;

__device__ inline short f2bf(float f) {
    unsigned u = __builtin_bit_cast(unsigned, f);
    u += 0x7FFFu + ((u >> 16) & 1u);          // RNE
    return (short)(u >> 16);
}
__device__ inline float bf2f(short h) {
    unsigned u = ((unsigned)(unsigned short)h) << 16;
    return __builtin_bit_cast(float, u);
}
__device__ inline float blo(unsigned u) { return __builtin_bit_cast(float, u << 16); }
__device__ inline float bhi(unsigned u) { return __builtin_bit_cast(float, u & 0xFFFF0000u); }
// pack: bits[15:0]=hi bf16, bits[31:16]=lo bf16
__device__ inline unsigned hilo_pack(float f) {
    short h = f2bf(f);
    short l = f2bf(f - bf2f(h));
    return ((unsigned)(unsigned short)h) | (((unsigned)(unsigned short)l) << 16);
}

// ------ init: zero deg + wconv + bounds + xb=bf16(relu(x)) + xhi/xlo -------
__global__ void init_kernel(const float* __restrict__ w0, const float* __restrict__ w1,
                            const float* __restrict__ w2, const float* __restrict__ w3,
                            const float* __restrict__ w4, const float* __restrict__ w5,
                            short* __restrict__ whi, short* __restrict__ wlo,
                            int* __restrict__ deg, const int* __restrict__ batch,
                            int* __restrict__ gstart,
                            const float* __restrict__ x, short* __restrict__ xb,
                            short* __restrict__ xhi, short* __restrict__ xlo, int N) {
    int idx = blockIdx.x * 256 + threadIdx.x;
    if (idx < N * (K_DIM / 4)) {
        float4 v = reinterpret_cast<const float4*>(x)[idx];
        unsigned px = hilo_pack(v.x), py = hilo_pack(v.y);
        unsigned pz = hilo_pack(v.z), pw = hilo_pack(v.w);
        short4v b, hh, ll;
        b[0] = f2bf(fmaxf(v.x, 0.f)); hh[0] = (short)(px & 0xFFFFu); ll[0] = (short)(px >> 16);
        b[1] = f2bf(fmaxf(v.y, 0.f)); hh[1] = (short)(py & 0xFFFFu); ll[1] = (short)(py >> 16);
        b[2] = f2bf(fmaxf(v.z, 0.f)); hh[2] = (short)(pz & 0xFFFFu); ll[2] = (short)(pz >> 16);
        b[3] = f2bf(fmaxf(v.w, 0.f)); hh[3] = (short)(pw & 0xFFFFu); ll[3] = (short)(pw >> 16);
        *reinterpret_cast<short4v*>(&xb [idx * 4]) = b;
        *reinterpret_cast<short4v*>(&xhi[idx * 4]) = hh;
        *reinterpret_cast<short4v*>(&xlo[idx * 4]) = ll;
    }
    if (idx < N) deg[idx] = 0;
    const int TOT = 4 * 16384 + 96 * 128;   // 77824
    if (idx < TOT) {
        float v;
        if (idx < 65536) {
            int m = idx >> 14, e = idx & 16383;
            const float* W = (m == 0) ? w0 : (m == 1) ? w1 : (m == 2) ? w2 : w3;
            v = W[e];
        } else {
            int i2 = idx - 65536;
            int row = i2 >> 7, col = i2 & 127;
            if (row < 40)      v = w4[row * 128 + col];
            else if (row < 80) v = w5[(row - 40) * 128 + col];
            else               v = 0.f;
        }
        unsigned p = hilo_pack(v);
        whi[idx] = (short)(p & 0xFFFFu);
        wlo[idx] = (short)(p >> 16);
    }
    if (idx <= N_GRAPHS) {
        int g = idx;
        int lo = 0, hi = N;
        while (lo < hi) {
            int mid = (lo + hi) >> 1;
            if (batch[mid] < g) lo = mid + 1; else hi = mid;
        }
        gstart[g] = lo;
    }
}

// ---------------- CSR build ----------------
__global__ void deg_kernel(const int* __restrict__ dst, int* __restrict__ deg, int E) {
    int e = blockIdx.x * blockDim.x + threadIdx.x;
    if (e < E) atomicAdd(&deg[dst[e]], 1);
}

__global__ void scan_p1(const int* __restrict__ deg, int* __restrict__ bsum, int N) {
    int i = blockIdx.x * 256 + threadIdx.x;
    int v = (i < N) ? deg[i] : 0;
    #pragma unroll
    for (int off = 32; off > 0; off >>= 1) v += __shfl_down(v, off, 64);
    __shared__ int ws[4];
    int lane = threadIdx.x & 63, wv = threadIdx.x >> 6;
    if (lane == 0) ws[wv] = v;
    __syncthreads();
    if (threadIdx.x == 0) bsum[blockIdx.x] = ws[0] + ws[1] + ws[2] + ws[3];
}

// merged p2+p3: each block locally exclusive-scans bsum, then writes its chunk
__global__ void scan_p23(const int* __restrict__ deg, const int* __restrict__ bsum,
                         int* __restrict__ rowptr, int* __restrict__ fillpos,
                         int N, int NB) {
    const int tid = threadIdx.x, lane = tid & 63, wv = tid >> 6;
    __shared__ int ws[4];
    __shared__ int sboff[256];
    {
        int v = (tid < NB) ? bsum[tid] : 0;
        int incl = v;
        #pragma unroll
        for (int off = 1; off < 64; off <<= 1) {
            int t = __shfl_up(incl, off, 64);
            if (lane >= off) incl += t;
        }
        if (lane == 63) ws[wv] = incl;
        __syncthreads();
        int add = 0;
        for (int k = 0; k < wv; ++k) add += ws[k];
        sboff[tid] = incl + add - v;
        __syncthreads();
    }
    const int boff = sboff[blockIdx.x];
    int i = blockIdx.x * 256 + tid;
    int v = (i < N) ? deg[i] : 0;
    int incl = v;
    #pragma unroll
    for (int off = 1; off < 64; off <<= 1) {
        int t = __shfl_up(incl, off, 64);
        if (lane >= off) incl += t;
    }
    __shared__ int ws2[4];
    if (lane == 63) ws2[wv] = incl;
    __syncthreads();
    int add = 0;
    for (int k = 0; k < wv; ++k) add += ws2[k];
    int excl = boff + incl + add - v;
    if (i < N) { rowptr[i] = excl; fillpos[i] = excl; }
    if (i == N) rowptr[N] = excl;
}

__global__ void fill_kernel(const int* __restrict__ src, const int* __restrict__ dst,
                            int* __restrict__ fillpos, int* __restrict__ csr_src, int E) {
    int e = blockIdx.x * blockDim.x + threadIdx.x;
    if (e < E) {
        int p = atomicAdd(&fillpos[dst[e]], 1);
        csr_src[p] = src[e];
    }
}

// ------- XCD-quarter aggregation: quarter q = blockIdx&3 -> XCD pair -------
// Wave handles one node's quarter: 16 lanes x uint (32 dims = 64B rows),
// 4 edges concurrent (g16), unroll-4 => 16 loads in flight.
__global__ void agg_bf16_q(const unsigned short* __restrict__ hb,
                           const int* __restrict__ rowptr,
                           const int* __restrict__ csr_src,
                           short* __restrict__ aggb, int N) {
    const int bI = blockIdx.x;
    const int q  = bI & 3;                       // feature quarter
    const int node = (bI >> 2) * 4 + (threadIdx.x >> 6);
    if (node >= N) return;
    const int lane = threadIdx.x & 63;
    const int g16 = lane >> 4, d16 = lane & 15;
    const int s = rowptr[node], e = rowptr[node + 1];
    const unsigned* tab = reinterpret_cast<const unsigned*>(hb) + q * 16 + d16;
    float ax = 0.f, ay = 0.f;
    int i = s + g16;
    for (; i + 12 < e; i += 16) {
        int s0 = csr_src[i], s1 = csr_src[i + 4], s2 = csr_src[i + 8], s3 = csr_src[i + 12];
        unsigned v0 = tab[(size_t)s0 * 64];
        unsigned v1 = tab[(size_t)s1 * 64];
        unsigned v2 = tab[(size_t)s2 * 64];
        unsigned v3 = tab[(size_t)s3 * 64];
        ax += (blo(v0) + blo(v1)) + (blo(v2) + blo(v3));
        ay += (bhi(v0) + bhi(v1)) + (bhi(v2) + bhi(v3));
    }
    for (; i < e; i += 4) {
        unsigned v0 = tab[(size_t)csr_src[i] * 64];
        ax += blo(v0); ay += bhi(v0);
    }
    ax += __shfl_xor(ax, 16, 64);
    ay += __shfl_xor(ay, 16, 64);
    ax += __shfl_xor(ax, 32, 64);
    ay += __shfl_xor(ay, 32, 64);
    if (g16 == 0) {
        float inv = 1.0f / fmaxf((float)(e - s), 1.0f);
        unsigned p = ((unsigned)(unsigned short)f2bf(ax * inv))
                   | (((unsigned)(unsigned short)f2bf(ay * inv)) << 16);
        reinterpret_cast<unsigned*>(aggb)[(size_t)node * 64 + q * 16 + d16] = p;
    }
}

// --------- MFMA layer GEMM: out = aggb@Wl^T + bl + H@Wr^T, relu ------------
// A = single bf16 (2 MFMAs); H = hi/lo planes (3 MFMAs). Raw-copy staging.
__global__ __launch_bounds__(256) void sage_mfma(
        const short* __restrict__ Ab_in,
        const short* __restrict__ Hhi_in, const short* __restrict__ Hlo_in,
        const short* __restrict__ Bhl, const short* __restrict__ Bll,
        const short* __restrict__ Bhr, const short* __restrict__ Blr,
        const float* __restrict__ bl,
        short* __restrict__ outHi, short* __restrict__ outLo, int N) {
    constexpr int BM = 64;
    constexpr int LSTR = 40;
    const int tid = threadIdx.x;
    const int lane = tid & 63;
    const int wave = tid >> 6;
    const int l15 = lane & 15;
    const int quad = lane >> 4;
    const int m0 = blockIdx.x * BM;
    const int srow = tid >> 2, sc8 = tid & 3;

    __shared__ __align__(16) short Ahi[BM * LSTR];
    __shared__ __align__(16) short Alo[BM * LSTR];

    f32x4 acc[4][2];
    #pragma unroll
    for (int i = 0; i < 4; ++i)
        #pragma unroll
        for (int j = 0; j < 2; ++j) acc[i][j] = (f32x4){0.f, 0.f, 0.f, 0.f};

    const short8 zero8 = (short8){0, 0, 0, 0, 0, 0, 0, 0};
    const int sm = m0 + srow;

    // ---- phase A: aggb (single bf16) @ Wl^T ----
    for (int k0 = 0; k0 < K_DIM; k0 += 32) {
        __syncthreads();
        {
            short8 v = zero8;
            if (sm < N) v = *reinterpret_cast<const short8*>(Ab_in + (size_t)sm * K_DIM + k0 + sc8 * 8);
            *reinterpret_cast<short8*>(&Ahi[srow * LSTR + sc8 * 8]) = v;
        }
        short8 bh[2], bo[2];
        #pragma unroll
        for (int nt = 0; nt < 2; ++nt) {
            int n = wave * 32 + nt * 16 + l15;
            bh[nt] = *reinterpret_cast<const short8*>(Bhl + (size_t)n * K_DIM + k0 + quad * 8);
            bo[nt] = *reinterpret_cast<const short8*>(Bll + (size_t)n * K_DIM + k0 + quad * 8);
        }
        __syncthreads();
        #pragma unroll
        for (int mt = 0; mt < 4; ++mt) {
            int row = mt * 16 + l15;
            short8 ab = *reinterpret_cast<const short8*>(&Ahi[row * LSTR + quad * 8]);
            #pragma unroll
            for (int nt = 0; nt < 2; ++nt) {
                acc[mt][nt] = __builtin_amdgcn_mfma_f32_16x16x32_bf16(ab, bh[nt], acc[mt][nt], 0, 0, 0);
                acc[mt][nt] = __builtin_amdgcn_mfma_f32_16x16x32_bf16(ab, bo[nt], acc[mt][nt], 0, 0, 0);
            }
        }
    }

    // ---- phase B: H (hi/lo planes) @ Wr^T ----
    for (int k0 = 0; k0 < K_DIM; k0 += 32) {
        __syncthreads();
        {
            short8 vh = zero8, vl = zero8;
            if (sm < N) {
                vh = *reinterpret_cast<const short8*>(Hhi_in + (size_t)sm * K_DIM + k0 + sc8 * 8);
                vl = *reinterpret_cast<const short8*>(Hlo_in + (size_t)sm * K_DIM + k0 + sc8 * 8);
            }
            *reinterpret_cast<short8*>(&Ahi[srow * LSTR + sc8 * 8]) = vh;
            *reinterpret_cast<short8*>(&Alo[srow * LSTR + sc8 * 8]) = vl;
        }
        short8 bh[2], bo[2];
        #pragma unroll
        for (int nt = 0; nt < 2; ++nt) {
            int n = wave * 32 + nt * 16 + l15;
            bh[nt] = *reinterpret_cast<const short8*>(Bhr + (size_t)n * K_DIM + k0 + quad * 8);
            bo[nt] = *reinterpret_cast<const short8*>(Blr + (size_t)n * K_DIM + k0 + quad * 8);
        }
        __syncthreads();
        #pragma unroll
        for (int mt = 0; mt < 4; ++mt) {
            int row = mt * 16 + l15;
            short8 ah = *reinterpret_cast<const short8*>(&Ahi[row * LSTR + quad * 8]);
            short8 ao = *reinterpret_cast<const short8*>(&Alo[row * LSTR + quad * 8]);
            #pragma unroll
            for (int nt = 0; nt < 2; ++nt) {
                acc[mt][nt] = __builtin_amdgcn_mfma_f32_16x16x32_bf16(ah, bh[nt], acc[mt][nt], 0, 0, 0);
                acc[mt][nt] = __builtin_amdgcn_mfma_f32_16x16x32_bf16(ah, bo[nt], acc[mt][nt], 0, 0, 0);
                acc[mt][nt] = __builtin_amdgcn_mfma_f32_16x16x32_bf16(ao, bh[nt], acc[mt][nt], 0, 0, 0);
            }
        }
    }

    // ---- epilogue: relu(acc + bias) -> hi/lo planes ----
    #pragma unroll
    for (int mt = 0; mt < 4; ++mt) {
        #pragma unroll
        for (int nt = 0; nt < 2; ++nt) {
            int col = wave * 32 + nt * 16 + l15;
            float b = bl[col];
            #pragma unroll
            for (int reg = 0; reg < 4; ++reg) {
                int row = m0 + mt * 16 + quad * 4 + reg;
                if (row < N) {
                    float v = fmaxf(acc[mt][nt][reg] + b, 0.f);
                    unsigned p = hilo_pack(v);
                    outHi[(size_t)row * K_DIM + col] = (short)(p & 0xFFFFu);
                    outLo[(size_t)row * K_DIM + col] = (short)(p >> 16);
                }
            }
        }
    }
}

// ------ layer-2 GEMM: ylb = bf16(h2@Wl2^T), yr40 = h2@Wr2^T + bl2 ----------
__global__ __launch_bounds__(256) void gemm80(
        const short* __restrict__ Xhi, const short* __restrict__ Xlo,
        const short* __restrict__ Bh, const short* __restrict__ Bv,
        const float* __restrict__ b2,
        short* __restrict__ ylb, float* __restrict__ yr40, int N) {
    constexpr int BM = 64;
    constexpr int LSTR = 40;
    const int tid = threadIdx.x;
    const int lane = tid & 63;
    const int wave = tid >> 6;
    const int wm = wave & 1;
    const int wn = wave >> 1;
    const int l15 = lane & 15;
    const int quad = lane >> 4;
    const int m0 = blockIdx.x * BM;
    const int srow = tid >> 2, sc8 = tid & 3;

    __shared__ __align__(16) short Ahi[BM * LSTR];
    __shared__ __align__(16) short Alo[BM * LSTR];

    f32x4 acc[2][3];
    #pragma unroll
    for (int i = 0; i < 2; ++i)
        #pragma unroll
        for (int j = 0; j < 3; ++j) acc[i][j] = (f32x4){0.f, 0.f, 0.f, 0.f};

    const short8 zero8 = (short8){0, 0, 0, 0, 0, 0, 0, 0};
    const int sm = m0 + srow;

    for (int k0 = 0; k0 < K_DIM; k0 += 32) {
        __syncthreads();
        {
            short8 vh = zero8, vl = zero8;
            if (sm < N) {
                vh = *reinterpret_cast<const short8*>(Xhi + (size_t)sm * K_DIM + k0 + sc8 * 8);
                vl = *reinterpret_cast<const short8*>(Xlo + (size_t)sm * K_DIM + k0 + sc8 * 8);
            }
            *reinterpret_cast<short8*>(&Ahi[srow * LSTR + sc8 * 8]) = vh;
            *reinterpret_cast<short8*>(&Alo[srow * LSTR + sc8 * 8]) = vl;
        }
        short8 bh[3], bo[3];
        #pragma unroll
        for (int nt = 0; nt < 3; ++nt) {
            int n = wn * 48 + nt * 16 + l15;   // < 96
            bh[nt] = *reinterpret_cast<const short8*>(Bh + (size_t)n * K_DIM + k0 + quad * 8);
            bo[nt] = *reinterpret_cast<const short8*>(Bv + (size_t)n * K_DIM + k0 + quad * 8);
        }
        __syncthreads();
        #pragma unroll
        for (int mt = 0; mt < 2; ++mt) {
            int row = wm * 32 + mt * 16 + l15;
            short8 ah = *reinterpret_cast<const short8*>(&Ahi[row * LSTR + quad * 8]);
            short8 ao = *reinterpret_cast<const short8*>(&Alo[row * LSTR + quad * 8]);
            #pragma unroll
            for (int nt = 0; nt < 3; ++nt) {
                acc[mt][nt] = __builtin_amdgcn_mfma_f32_16x16x32_bf16(ah, bh[nt], acc[mt][nt], 0, 0, 0);
                acc[mt][nt] = __builtin_amdgcn_mfma_f32_16x16x32_bf16(ah, bo[nt], acc[mt][nt], 0, 0, 0);
                acc[mt][nt] = __builtin_amdgcn_mfma_f32_16x16x32_bf16(ao, bh[nt], acc[mt][nt], 0, 0, 0);
            }
        }
    }

    #pragma unroll
    for (int mt = 0; mt < 2; ++mt) {
        #pragma unroll
        for (int nt = 0; nt < 3; ++nt) {
            int col = wn * 48 + nt * 16 + l15;
            #pragma unroll
            for (int reg = 0; reg < 4; ++reg) {
                int row = m0 + wm * 32 + mt * 16 + quad * 4 + reg;
                if (row < N) {
                    float v = acc[mt][nt][reg];
                    if (col < 40) {
                        ylb[(size_t)row * 40 + col] = f2bf(v);
                    } else if (col < 80) {
                        yr40[(size_t)row * 40 + (col - 40)] = v + b2[col - 40];
                    }
                }
            }
        }
    }
}

// ------- agg40: out[n] = mean_e bf16 ylb[src_e] + yr40[n] ------------------
__global__ void agg40_kernel(const unsigned short* __restrict__ ylb,
                             const float* __restrict__ yr40,
                             const int* __restrict__ rowptr, const int* __restrict__ csr_src,
                             float* __restrict__ out, int N) {
    int w = (blockIdx.x * blockDim.x + threadIdx.x) >> 6;
    if (w >= N) return;
    int lane = threadIdx.x & 63;
    int s = rowptr[w], e = rowptr[w + 1];
    if (lane >= 40) return;
    float acc = 0.f;
    int i = s;
    for (; i + 3 < e; i += 4) {
        int s0 = csr_src[i], s1 = csr_src[i + 1], s2 = csr_src[i + 2], s3 = csr_src[i + 3];
        float v0 = bf2f((short)ylb[(size_t)s0 * 40 + lane]);
        float v1 = bf2f((short)ylb[(size_t)s1 * 40 + lane]);
        float v2 = bf2f((short)ylb[(size_t)s2 * 40 + lane]);
        float v3 = bf2f((short)ylb[(size_t)s3 * 40 + lane]);
        acc += (v0 + v1) + (v2 + v3);
    }
    for (; i < e; ++i) acc += bf2f((short)ylb[(size_t)csr_src[i] * 40 + lane]);
    float inv = 1.0f / fmaxf((float)(e - s), 1.0f);
    out[(size_t)w * 40 + lane] = acc * inv + yr40[(size_t)w * 40 + lane];
}

// ---------------- pool ----------------
__global__ __launch_bounds__(320) void pool_kernel(const float* __restrict__ h,
                                                   const int* __restrict__ gstart,
                                                   float* __restrict__ g_out) {
    int g = blockIdx.x;
    int tid = threadIdx.x;
    int c = tid % 40, r = tid / 40;
    int s = gstart[g], e = gstart[g + 1];
    float acc = 0.f;
    for (int n = s + r; n < e; n += 8)
        acc += h[(size_t)n * 40 + c];
    __shared__ float sh[8][40];
    sh[r][c] = acc;
    __syncthreads();
    if (r == 0) {
        float sum = 0.f;
        #pragma unroll
        for (int i = 0; i < 8; ++i) sum += sh[i][c];
        g_out[g * 40 + c] = sum / fmaxf((float)(e - s), 1.0f);
    }
}

extern "C" void kernel_launch(void* const* d_in, const int* in_sizes, int n_in,
                              void* d_out, int out_size, void* d_ws, size_t ws_size,
                              hipStream_t stream) {
    const float* x    = (const float*)d_in[0];
    const int*   ei   = (const int*)d_in[1];
    const int*   batch= (const int*)d_in[2];
    const float* Wl0  = (const float*)d_in[3];
    const float* bl0  = (const float*)d_in[4];
    const float* Wr0  = (const float*)d_in[5];
    const float* Wl1  = (const float*)d_in[6];
    const float* bl1  = (const float*)d_in[7];
    const float* Wr1  = (const float*)d_in[8];
    const float* Wl2  = (const float*)d_in[9];
    const float* bl2  = (const float*)d_in[10];
    const float* Wr2  = (const float*)d_in[11];

    const int N = in_sizes[0] / K_DIM;       // 50000
    const int E = in_sizes[1] / 2;           // 600000
    const int* src = ei;
    const int* dst = ei + E;

    float* out = (float*)d_out;              // h3 [N,40] then g [128,40]
    float* gsum = out + (size_t)N * 40;

    char* w = (char*)d_ws;
    auto alloc = [&](size_t bytes) {
        char* p = w;
        w += (bytes + 255) & ~(size_t)255;
        return p;
    };
    const size_t PL = (size_t)N * K_DIM * 2;  // one bf16 plane = 12.8 MB
    short* aggb  = (short*)alloc(PL);
    short* xb    = (short*)alloc(PL);
    short* xhi   = (short*)alloc(PL);
    short* xlo   = (short*)alloc(PL);
    short* h1hi  = (short*)alloc(PL);
    short* h1lo  = (short*)alloc(PL);
    short* h2hi  = (short*)alloc(PL);
    short* h2lo  = (short*)alloc(PL);
    short* ylb   = (short*)alloc((size_t)N * 40 * 2);
    float* yr40  = (float*)alloc((size_t)N * 40 * 4);
    int*   rowptr= (int*)alloc((size_t)(N + 1) * 4);
    int*   deg   = (int*)alloc((size_t)N * 4);
    int*   fillp = (int*)alloc((size_t)N * 4);
    int*   csr   = (int*)alloc((size_t)E * 4);
    int*   bsum  = (int*)alloc(256 * 4);
    int*   gstart= (int*)alloc((size_t)(N_GRAPHS + 1) * 4);
    short* whi   = (short*)alloc(77824 * 2);
    short* wlo   = (short*)alloc(77824 * 2);

    const int NB = (N + 255) / 256;              // 196
    const int initGrid = (N * (K_DIM / 4) + 255) / 256;   // 6250

    init_kernel<<<initGrid, 256, 0, stream>>>(Wl0, Wr0, Wl1, Wr1, Wl2, Wr2,
                                              whi, wlo, deg, batch, gstart,
                                              x, xb, xhi, xlo, N);
    deg_kernel<<<(E + 255) / 256, 256, 0, stream>>>(dst, deg, E);
    scan_p1<<<NB, 256, 0, stream>>>(deg, bsum, N);
    scan_p23<<<NB, 256, 0, stream>>>(deg, bsum, rowptr, fillp, N, NB);
    fill_kernel<<<(E + 255) / 256, 256, 0, stream>>>(src, dst, fillp, csr, E);

    short* hWl0 = whi;          short* lWl0 = wlo;
    short* hWr0 = whi + 16384;  short* lWr0 = wlo + 16384;
    short* hWl1 = whi + 32768;  short* lWl1 = wlo + 32768;
    short* hWr1 = whi + 49152;  short* lWr1 = wlo + 49152;
    short* hW2  = whi + 65536;  short* lW2  = wlo + 65536;

    const int aggQGrid = ((N + 3) / 4) * 4;      // 50000: (nodegroup, quarter)
    const int aggGrid  = (N * 64 + 255) / 256;   // 12500
    const int gemmGrid = (N + 63) / 64;          // 782

    // layer 0
    agg_bf16_q<<<aggQGrid, 256, 0, stream>>>((const unsigned short*)xb, rowptr, csr, aggb, N);
    sage_mfma<<<gemmGrid, 256, 0, stream>>>(
        aggb, xhi, xlo, hWl0, lWl0, hWr0, lWr0, bl0, h1hi, h1lo, N);
    // layer 1 (h1hi doubles as the gather table: h1 >= 0)
    agg_bf16_q<<<aggQGrid, 256, 0, stream>>>((const unsigned short*)h1hi, rowptr, csr, aggb, N);
    sage_mfma<<<gemmGrid, 256, 0, stream>>>(
        aggb, h1hi, h1lo, hWl1, lWl1, hWr1, lWr1, bl1, h2hi, h2lo, N);
    // layer 2
    gemm80<<<gemmGrid, 256, 0, stream>>>(h2hi, h2lo, hW2, lW2, bl2, ylb, yr40, N);
    agg40_kernel<<<aggGrid, 256, 0, stream>>>((const unsigned short*)ylb, yr40, rowptr, csr, out, N);

    // global mean pool
    pool_kernel<<<N_GRAPHS, 320, 0, stream>>>(out, gstart, gsum);
}

// Round 14
// 333.613 us; speedup vs baseline: 1.2904x; 1.2904x over previous
//
#include <hip/hip_runtime.h>
#include <hip/hip_bf16.h>

// ---------------------------------------------------------------------------
// GraphSAGE 3-layer + global mean pool, fp32 in/out.
//   layer: agg = mean_{e:dst=n} relu(h[src_e]);  h' = agg@Wl^T + bl + h@Wr^T
// R1: sorted-batch pool -> segment reduction.                 810->537us
// R2: parallel scan + wave64 agg + relu-elision.              537->449us
// R3-R5: bf16 MFMA hi/lo split GEMM (3 MFMAs, fp32-class).    449->387us
// R6: layer-2 linearity swap (gather 40-dim not 128-dim).     387->378us
// R7/R8/R9: structural fusions all REGRESSED, reverted.
// R10: union of proven pieces, 13 dispatches.                 378->360us
// R11: bf16 gather tables (2x fewer gather bytes).            360->337us
// R12: plane-ized GEMM inputs: NEUTRAL (GEMMs not staging-bound). 338us
// R13: XCD-quarter gather REGRESSED (78us: 4x request count; gather is
//     request-rate-limited, not byte-limited). REVERTED.
// R14: back to R12 config = best measured. Gather at ~27us is at the
//     random-gather service floor for this graph (ILP+, edge-parallel-,
//     quartering-, byte-halving+small all measured).
// ---------------------------------------------------------------------------

#define NODES 50000
#define K_DIM 128
#define N_GRAPHS 128

typedef __attribute__((ext_vector_type(8))) short short8;
typedef __attribute__((ext_vector_type(4))) short short4v;
typedef __attribute__((ext_vector_type(4))) float f32x4;

__device__ inline short f2bf(float f) {
    unsigned u = __builtin_bit_cast(unsigned, f);
    u += 0x7FFFu + ((u >> 16) & 1u);          // RNE
    return (short)(u >> 16);
}
__device__ inline float bf2f(short h) {
    unsigned u = ((unsigned)(unsigned short)h) << 16;
    return __builtin_bit_cast(float, u);
}
__device__ inline float blo(unsigned u) { return __builtin_bit_cast(float, u << 16); }
__device__ inline float bhi(unsigned u) { return __builtin_bit_cast(float, u & 0xFFFF0000u); }
// pack: bits[15:0]=hi bf16, bits[31:16]=lo bf16
__device__ inline unsigned hilo_pack(float f) {
    short h = f2bf(f);
    short l = f2bf(f - bf2f(h));
    return ((unsigned)(unsigned short)h) | (((unsigned)(unsigned short)l) << 16);
}

// ------ init: zero deg + wconv + bounds + xb=bf16(relu(x)) + xhi/xlo -------
__global__ void init_kernel(const float* __restrict__ w0, const float* __restrict__ w1,
                            const float* __restrict__ w2, const float* __restrict__ w3,
                            const float* __restrict__ w4, const float* __restrict__ w5,
                            short* __restrict__ whi, short* __restrict__ wlo,
                            int* __restrict__ deg, const int* __restrict__ batch,
                            int* __restrict__ gstart,
                            const float* __restrict__ x, short* __restrict__ xb,
                            short* __restrict__ xhi, short* __restrict__ xlo, int N) {
    int idx = blockIdx.x * 256 + threadIdx.x;
    if (idx < N * (K_DIM / 4)) {
        float4 v = reinterpret_cast<const float4*>(x)[idx];
        unsigned px = hilo_pack(v.x), py = hilo_pack(v.y);
        unsigned pz = hilo_pack(v.z), pw = hilo_pack(v.w);
        short4v b, hh, ll;
        b[0] = f2bf(fmaxf(v.x, 0.f)); hh[0] = (short)(px & 0xFFFFu); ll[0] = (short)(px >> 16);
        b[1] = f2bf(fmaxf(v.y, 0.f)); hh[1] = (short)(py & 0xFFFFu); ll[1] = (short)(py >> 16);
        b[2] = f2bf(fmaxf(v.z, 0.f)); hh[2] = (short)(pz & 0xFFFFu); ll[2] = (short)(pz >> 16);
        b[3] = f2bf(fmaxf(v.w, 0.f)); hh[3] = (short)(pw & 0xFFFFu); ll[3] = (short)(pw >> 16);
        *reinterpret_cast<short4v*>(&xb [idx * 4]) = b;
        *reinterpret_cast<short4v*>(&xhi[idx * 4]) = hh;
        *reinterpret_cast<short4v*>(&xlo[idx * 4]) = ll;
    }
    if (idx < N) deg[idx] = 0;
    const int TOT = 4 * 16384 + 96 * 128;   // 77824
    if (idx < TOT) {
        float v;
        if (idx < 65536) {
            int m = idx >> 14, e = idx & 16383;
            const float* W = (m == 0) ? w0 : (m == 1) ? w1 : (m == 2) ? w2 : w3;
            v = W[e];
        } else {
            int i2 = idx - 65536;
            int row = i2 >> 7, col = i2 & 127;
            if (row < 40)      v = w4[row * 128 + col];
            else if (row < 80) v = w5[(row - 40) * 128 + col];
            else               v = 0.f;
        }
        unsigned p = hilo_pack(v);
        whi[idx] = (short)(p & 0xFFFFu);
        wlo[idx] = (short)(p >> 16);
    }
    if (idx <= N_GRAPHS) {
        int g = idx;
        int lo = 0, hi = N;
        while (lo < hi) {
            int mid = (lo + hi) >> 1;
            if (batch[mid] < g) lo = mid + 1; else hi = mid;
        }
        gstart[g] = lo;
    }
}

// ---------------- CSR build ----------------
__global__ void deg_kernel(const int* __restrict__ dst, int* __restrict__ deg, int E) {
    int e = blockIdx.x * blockDim.x + threadIdx.x;
    if (e < E) atomicAdd(&deg[dst[e]], 1);
}

__global__ void scan_p1(const int* __restrict__ deg, int* __restrict__ bsum, int N) {
    int i = blockIdx.x * 256 + threadIdx.x;
    int v = (i < N) ? deg[i] : 0;
    #pragma unroll
    for (int off = 32; off > 0; off >>= 1) v += __shfl_down(v, off, 64);
    __shared__ int ws[4];
    int lane = threadIdx.x & 63, wv = threadIdx.x >> 6;
    if (lane == 0) ws[wv] = v;
    __syncthreads();
    if (threadIdx.x == 0) bsum[blockIdx.x] = ws[0] + ws[1] + ws[2] + ws[3];
}

// merged p2+p3: each block locally exclusive-scans bsum, then writes its chunk
__global__ void scan_p23(const int* __restrict__ deg, const int* __restrict__ bsum,
                         int* __restrict__ rowptr, int* __restrict__ fillpos,
                         int N, int NB) {
    const int tid = threadIdx.x, lane = tid & 63, wv = tid >> 6;
    __shared__ int ws[4];
    __shared__ int sboff[256];
    {
        int v = (tid < NB) ? bsum[tid] : 0;
        int incl = v;
        #pragma unroll
        for (int off = 1; off < 64; off <<= 1) {
            int t = __shfl_up(incl, off, 64);
            if (lane >= off) incl += t;
        }
        if (lane == 63) ws[wv] = incl;
        __syncthreads();
        int add = 0;
        for (int k = 0; k < wv; ++k) add += ws[k];
        sboff[tid] = incl + add - v;
        __syncthreads();
    }
    const int boff = sboff[blockIdx.x];
    int i = blockIdx.x * 256 + tid;
    int v = (i < N) ? deg[i] : 0;
    int incl = v;
    #pragma unroll
    for (int off = 1; off < 64; off <<= 1) {
        int t = __shfl_up(incl, off, 64);
        if (lane >= off) incl += t;
    }
    __shared__ int ws2[4];
    if (lane == 63) ws2[wv] = incl;
    __syncthreads();
    int add = 0;
    for (int k = 0; k < wv; ++k) add += ws2[k];
    int excl = boff + incl + add - v;
    if (i < N) { rowptr[i] = excl; fillpos[i] = excl; }
    if (i == N) rowptr[N] = excl;
}

__global__ void fill_kernel(const int* __restrict__ src, const int* __restrict__ dst,
                            int* __restrict__ fillpos, int* __restrict__ csr_src, int E) {
    int e = blockIdx.x * blockDim.x + threadIdx.x;
    if (e < E) {
        int p = atomicAdd(&fillpos[dst[e]], 1);
        csr_src[p] = src[e];
    }
}

// ------- aggregation from bf16 table (128-dim) -> bf16 mean ----------------
__global__ void agg_bf16(const unsigned short* __restrict__ hb,
                         const int* __restrict__ rowptr,
                         const int* __restrict__ csr_src,
                         short* __restrict__ aggb, int N) {
    int w = (blockIdx.x * blockDim.x + threadIdx.x) >> 6;
    if (w >= N) return;
    int lane = threadIdx.x & 63;
    int half = lane >> 5, l32 = lane & 31;
    int s = rowptr[w], e = rowptr[w + 1];
    float4 acc = make_float4(0.f, 0.f, 0.f, 0.f);
    int i = s + half;
    for (; i + 6 < e; i += 8) {
        int s0 = csr_src[i], s1 = csr_src[i + 2], s2 = csr_src[i + 4], s3 = csr_src[i + 6];
        uint2 v0 = reinterpret_cast<const uint2*>(hb + (size_t)s0 * K_DIM)[l32];
        uint2 v1 = reinterpret_cast<const uint2*>(hb + (size_t)s1 * K_DIM)[l32];
        uint2 v2 = reinterpret_cast<const uint2*>(hb + (size_t)s2 * K_DIM)[l32];
        uint2 v3 = reinterpret_cast<const uint2*>(hb + (size_t)s3 * K_DIM)[l32];
        acc.x += (blo(v0.x) + blo(v1.x)) + (blo(v2.x) + blo(v3.x));
        acc.y += (bhi(v0.x) + bhi(v1.x)) + (bhi(v2.x) + bhi(v3.x));
        acc.z += (blo(v0.y) + blo(v1.y)) + (blo(v2.y) + blo(v3.y));
        acc.w += (bhi(v0.y) + bhi(v1.y)) + (bhi(v2.y) + bhi(v3.y));
    }
    for (; i < e; i += 2) {
        int s0 = csr_src[i];
        uint2 v0 = reinterpret_cast<const uint2*>(hb + (size_t)s0 * K_DIM)[l32];
        acc.x += blo(v0.x); acc.y += bhi(v0.x);
        acc.z += blo(v0.y); acc.w += bhi(v0.y);
    }
    acc.x += __shfl_xor(acc.x, 32, 64);
    acc.y += __shfl_xor(acc.y, 32, 64);
    acc.z += __shfl_xor(acc.z, 32, 64);
    acc.w += __shfl_xor(acc.w, 32, 64);
    if (half == 0) {
        float inv = 1.0f / fmaxf((float)(e - s), 1.0f);
        short4v b;
        b[0] = f2bf(acc.x * inv);
        b[1] = f2bf(acc.y * inv);
        b[2] = f2bf(acc.z * inv);
        b[3] = f2bf(acc.w * inv);
        *reinterpret_cast<short4v*>(&aggb[(size_t)w * K_DIM + l32 * 4]) = b;
    }
}

// --------- MFMA layer GEMM: out = aggb@Wl^T + bl + H@Wr^T, relu ------------
// A = single bf16 (2 MFMAs); H = hi/lo planes (3 MFMAs). Raw-copy staging.
__global__ __launch_bounds__(256) void sage_mfma(
        const short* __restrict__ Ab_in,
        const short* __restrict__ Hhi_in, const short* __restrict__ Hlo_in,
        const short* __restrict__ Bhl, const short* __restrict__ Bll,
        const short* __restrict__ Bhr, const short* __restrict__ Blr,
        const float* __restrict__ bl,
        short* __restrict__ outHi, short* __restrict__ outLo, int N) {
    constexpr int BM = 64;
    constexpr int LSTR = 40;
    const int tid = threadIdx.x;
    const int lane = tid & 63;
    const int wave = tid >> 6;
    const int l15 = lane & 15;
    const int quad = lane >> 4;
    const int m0 = blockIdx.x * BM;
    const int srow = tid >> 2, sc8 = tid & 3;

    __shared__ __align__(16) short Ahi[BM * LSTR];
    __shared__ __align__(16) short Alo[BM * LSTR];

    f32x4 acc[4][2];
    #pragma unroll
    for (int i = 0; i < 4; ++i)
        #pragma unroll
        for (int j = 0; j < 2; ++j) acc[i][j] = (f32x4){0.f, 0.f, 0.f, 0.f};

    const short8 zero8 = (short8){0, 0, 0, 0, 0, 0, 0, 0};
    const int sm = m0 + srow;

    // ---- phase A: aggb (single bf16) @ Wl^T ----
    for (int k0 = 0; k0 < K_DIM; k0 += 32) {
        __syncthreads();
        {
            short8 v = zero8;
            if (sm < N) v = *reinterpret_cast<const short8*>(Ab_in + (size_t)sm * K_DIM + k0 + sc8 * 8);
            *reinterpret_cast<short8*>(&Ahi[srow * LSTR + sc8 * 8]) = v;
        }
        short8 bh[2], bo[2];
        #pragma unroll
        for (int nt = 0; nt < 2; ++nt) {
            int n = wave * 32 + nt * 16 + l15;
            bh[nt] = *reinterpret_cast<const short8*>(Bhl + (size_t)n * K_DIM + k0 + quad * 8);
            bo[nt] = *reinterpret_cast<const short8*>(Bll + (size_t)n * K_DIM + k0 + quad * 8);
        }
        __syncthreads();
        #pragma unroll
        for (int mt = 0; mt < 4; ++mt) {
            int row = mt * 16 + l15;
            short8 ab = *reinterpret_cast<const short8*>(&Ahi[row * LSTR + quad * 8]);
            #pragma unroll
            for (int nt = 0; nt < 2; ++nt) {
                acc[mt][nt] = __builtin_amdgcn_mfma_f32_16x16x32_bf16(ab, bh[nt], acc[mt][nt], 0, 0, 0);
                acc[mt][nt] = __builtin_amdgcn_mfma_f32_16x16x32_bf16(ab, bo[nt], acc[mt][nt], 0, 0, 0);
            }
        }
    }

    // ---- phase B: H (hi/lo planes) @ Wr^T ----
    for (int k0 = 0; k0 < K_DIM; k0 += 32) {
        __syncthreads();
        {
            short8 vh = zero8, vl = zero8;
            if (sm < N) {
                vh = *reinterpret_cast<const short8*>(Hhi_in + (size_t)sm * K_DIM + k0 + sc8 * 8);
                vl = *reinterpret_cast<const short8*>(Hlo_in + (size_t)sm * K_DIM + k0 + sc8 * 8);
            }
            *reinterpret_cast<short8*>(&Ahi[srow * LSTR + sc8 * 8]) = vh;
            *reinterpret_cast<short8*>(&Alo[srow * LSTR + sc8 * 8]) = vl;
        }
        short8 bh[2], bo[2];
        #pragma unroll
        for (int nt = 0; nt < 2; ++nt) {
            int n = wave * 32 + nt * 16 + l15;
            bh[nt] = *reinterpret_cast<const short8*>(Bhr + (size_t)n * K_DIM + k0 + quad * 8);
            bo[nt] = *reinterpret_cast<const short8*>(Blr + (size_t)n * K_DIM + k0 + quad * 8);
        }
        __syncthreads();
        #pragma unroll
        for (int mt = 0; mt < 4; ++mt) {
            int row = mt * 16 + l15;
            short8 ah = *reinterpret_cast<const short8*>(&Ahi[row * LSTR + quad * 8]);
            short8 ao = *reinterpret_cast<const short8*>(&Alo[row * LSTR + quad * 8]);
            #pragma unroll
            for (int nt = 0; nt < 2; ++nt) {
                acc[mt][nt] = __builtin_amdgcn_mfma_f32_16x16x32_bf16(ah, bh[nt], acc[mt][nt], 0, 0, 0);
                acc[mt][nt] = __builtin_amdgcn_mfma_f32_16x16x32_bf16(ah, bo[nt], acc[mt][nt], 0, 0, 0);
                acc[mt][nt] = __builtin_amdgcn_mfma_f32_16x16x32_bf16(ao, bh[nt], acc[mt][nt], 0, 0, 0);
            }
        }
    }

    // ---- epilogue: relu(acc + bias) -> hi/lo planes ----
    #pragma unroll
    for (int mt = 0; mt < 4; ++mt) {
        #pragma unroll
        for (int nt = 0; nt < 2; ++nt) {
            int col = wave * 32 + nt * 16 + l15;
            float b = bl[col];
            #pragma unroll
            for (int reg = 0; reg < 4; ++reg) {
                int row = m0 + mt * 16 + quad * 4 + reg;
                if (row < N) {
                    float v = fmaxf(acc[mt][nt][reg] + b, 0.f);
                    unsigned p = hilo_pack(v);
                    outHi[(size_t)row * K_DIM + col] = (short)(p & 0xFFFFu);
                    outLo[(size_t)row * K_DIM + col] = (short)(p >> 16);
                }
            }
        }
    }
}

// ------ layer-2 GEMM: ylb = bf16(h2@Wl2^T), yr40 = h2@Wr2^T + bl2 ----------
__global__ __launch_bounds__(256) void gemm80(
        const short* __restrict__ Xhi, const short* __restrict__ Xlo,
        const short* __restrict__ Bh, const short* __restrict__ Bv,
        const float* __restrict__ b2,
        short* __restrict__ ylb, float* __restrict__ yr40, int N) {
    constexpr int BM = 64;
    constexpr int LSTR = 40;
    const int tid = threadIdx.x;
    const int lane = tid & 63;
    const int wave = tid >> 6;
    const int wm = wave & 1;
    const int wn = wave >> 1;
    const int l15 = lane & 15;
    const int quad = lane >> 4;
    const int m0 = blockIdx.x * BM;
    const int srow = tid >> 2, sc8 = tid & 3;

    __shared__ __align__(16) short Ahi[BM * LSTR];
    __shared__ __align__(16) short Alo[BM * LSTR];

    f32x4 acc[2][3];
    #pragma unroll
    for (int i = 0; i < 2; ++i)
        #pragma unroll
        for (int j = 0; j < 3; ++j) acc[i][j] = (f32x4){0.f, 0.f, 0.f, 0.f};

    const short8 zero8 = (short8){0, 0, 0, 0, 0, 0, 0, 0};
    const int sm = m0 + srow;

    for (int k0 = 0; k0 < K_DIM; k0 += 32) {
        __syncthreads();
        {
            short8 vh = zero8, vl = zero8;
            if (sm < N) {
                vh = *reinterpret_cast<const short8*>(Xhi + (size_t)sm * K_DIM + k0 + sc8 * 8);
                vl = *reinterpret_cast<const short8*>(Xlo + (size_t)sm * K_DIM + k0 + sc8 * 8);
            }
            *reinterpret_cast<short8*>(&Ahi[srow * LSTR + sc8 * 8]) = vh;
            *reinterpret_cast<short8*>(&Alo[srow * LSTR + sc8 * 8]) = vl;
        }
        short8 bh[3], bo[3];
        #pragma unroll
        for (int nt = 0; nt < 3; ++nt) {
            int n = wn * 48 + nt * 16 + l15;   // < 96
            bh[nt] = *reinterpret_cast<const short8*>(Bh + (size_t)n * K_DIM + k0 + quad * 8);
            bo[nt] = *reinterpret_cast<const short8*>(Bv + (size_t)n * K_DIM + k0 + quad * 8);
        }
        __syncthreads();
        #pragma unroll
        for (int mt = 0; mt < 2; ++mt) {
            int row = wm * 32 + mt * 16 + l15;
            short8 ah = *reinterpret_cast<const short8*>(&Ahi[row * LSTR + quad * 8]);
            short8 ao = *reinterpret_cast<const short8*>(&Alo[row * LSTR + quad * 8]);
            #pragma unroll
            for (int nt = 0; nt < 3; ++nt) {
                acc[mt][nt] = __builtin_amdgcn_mfma_f32_16x16x32_bf16(ah, bh[nt], acc[mt][nt], 0, 0, 0);
                acc[mt][nt] = __builtin_amdgcn_mfma_f32_16x16x32_bf16(ah, bo[nt], acc[mt][nt], 0, 0, 0);
                acc[mt][nt] = __builtin_amdgcn_mfma_f32_16x16x32_bf16(ao, bh[nt], acc[mt][nt], 0, 0, 0);
            }
        }
    }

    #pragma unroll
    for (int mt = 0; mt < 2; ++mt) {
        #pragma unroll
        for (int nt = 0; nt < 3; ++nt) {
            int col = wn * 48 + nt * 16 + l15;
            #pragma unroll
            for (int reg = 0; reg < 4; ++reg) {
                int row = m0 + wm * 32 + mt * 16 + quad * 4 + reg;
                if (row < N) {
                    float v = acc[mt][nt][reg];
                    if (col < 40) {
                        ylb[(size_t)row * 40 + col] = f2bf(v);
                    } else if (col < 80) {
                        yr40[(size_t)row * 40 + (col - 40)] = v + b2[col - 40];
                    }
                }
            }
        }
    }
}

// ------- agg40: out[n] = mean_e bf16 ylb[src_e] + yr40[n] ------------------
__global__ void agg40_kernel(const unsigned short* __restrict__ ylb,
                             const float* __restrict__ yr40,
                             const int* __restrict__ rowptr, const int* __restrict__ csr_src,
                             float* __restrict__ out, int N) {
    int w = (blockIdx.x * blockDim.x + threadIdx.x) >> 6;
    if (w >= N) return;
    int lane = threadIdx.x & 63;
    int s = rowptr[w], e = rowptr[w + 1];
    if (lane >= 40) return;
    float acc = 0.f;
    int i = s;
    for (; i + 3 < e; i += 4) {
        int s0 = csr_src[i], s1 = csr_src[i + 1], s2 = csr_src[i + 2], s3 = csr_src[i + 3];
        float v0 = bf2f((short)ylb[(size_t)s0 * 40 + lane]);
        float v1 = bf2f((short)ylb[(size_t)s1 * 40 + lane]);
        float v2 = bf2f((short)ylb[(size_t)s2 * 40 + lane]);
        float v3 = bf2f((short)ylb[(size_t)s3 * 40 + lane]);
        acc += (v0 + v1) + (v2 + v3);
    }
    for (; i < e; ++i) acc += bf2f((short)ylb[(size_t)csr_src[i] * 40 + lane]);
    float inv = 1.0f / fmaxf((float)(e - s), 1.0f);
    out[(size_t)w * 40 + lane] = acc * inv + yr40[(size_t)w * 40 + lane];
}

// ---------------- pool ----------------
__global__ __launch_bounds__(320) void pool_kernel(const float* __restrict__ h,
                                                   const int* __restrict__ gstart,
                                                   float* __restrict__ g_out) {
    int g = blockIdx.x;
    int tid = threadIdx.x;
    int c = tid % 40, r = tid / 40;
    int s = gstart[g], e = gstart[g + 1];
    float acc = 0.f;
    for (int n = s + r; n < e; n += 8)
        acc += h[(size_t)n * 40 + c];
    __shared__ float sh[8][40];
    sh[r][c] = acc;
    __syncthreads();
    if (r == 0) {
        float sum = 0.f;
        #pragma unroll
        for (int i = 0; i < 8; ++i) sum += sh[i][c];
        g_out[g * 40 + c] = sum / fmaxf((float)(e - s), 1.0f);
    }
}

extern "C" void kernel_launch(void* const* d_in, const int* in_sizes, int n_in,
                              void* d_out, int out_size, void* d_ws, size_t ws_size,
                              hipStream_t stream) {
    const float* x    = (const float*)d_in[0];
    const int*   ei   = (const int*)d_in[1];
    const int*   batch= (const int*)d_in[2];
    const float* Wl0  = (const float*)d_in[3];
    const float* bl0  = (const float*)d_in[4];
    const float* Wr0  = (const float*)d_in[5];
    const float* Wl1  = (const float*)d_in[6];
    const float* bl1  = (const float*)d_in[7];
    const float* Wr1  = (const float*)d_in[8];
    const float* Wl2  = (const float*)d_in[9];
    const float* bl2  = (const float*)d_in[10];
    const float* Wr2  = (const float*)d_in[11];

    const int N = in_sizes[0] / K_DIM;       // 50000
    const int E = in_sizes[1] / 2;           // 600000
    const int* src = ei;
    const int* dst = ei + E;

    float* out = (float*)d_out;              // h3 [N,40] then g [128,40]
    float* gsum = out + (size_t)N * 40;

    char* w = (char*)d_ws;
    auto alloc = [&](size_t bytes) {
        char* p = w;
        w += (bytes + 255) & ~(size_t)255;
        return p;
    };
    const size_t PL = (size_t)N * K_DIM * 2;  // one bf16 plane = 12.8 MB
    short* aggb  = (short*)alloc(PL);
    short* xb    = (short*)alloc(PL);
    short* xhi   = (short*)alloc(PL);
    short* xlo   = (short*)alloc(PL);
    short* h1hi  = (short*)alloc(PL);
    short* h1lo  = (short*)alloc(PL);
    short* h2hi  = (short*)alloc(PL);
    short* h2lo  = (short*)alloc(PL);
    short* ylb   = (short*)alloc((size_t)N * 40 * 2);
    float* yr40  = (float*)alloc((size_t)N * 40 * 4);
    int*   rowptr= (int*)alloc((size_t)(N + 1) * 4);
    int*   deg   = (int*)alloc((size_t)N * 4);
    int*   fillp = (int*)alloc((size_t)N * 4);
    int*   csr   = (int*)alloc((size_t)E * 4);
    int*   bsum  = (int*)alloc(256 * 4);
    int*   gstart= (int*)alloc((size_t)(N_GRAPHS + 1) * 4);
    short* whi   = (short*)alloc(77824 * 2);
    short* wlo   = (short*)alloc(77824 * 2);

    const int NB = (N + 255) / 256;              // 196
    const int initGrid = (N * (K_DIM / 4) + 255) / 256;   // 6250

    init_kernel<<<initGrid, 256, 0, stream>>>(Wl0, Wr0, Wl1, Wr1, Wl2, Wr2,
                                              whi, wlo, deg, batch, gstart,
                                              x, xb, xhi, xlo, N);
    deg_kernel<<<(E + 255) / 256, 256, 0, stream>>>(dst, deg, E);
    scan_p1<<<NB, 256, 0, stream>>>(deg, bsum, N);
    scan_p23<<<NB, 256, 0, stream>>>(deg, bsum, rowptr, fillp, N, NB);
    fill_kernel<<<(E + 255) / 256, 256, 0, stream>>>(src, dst, fillp, csr, E);

    short* hWl0 = whi;          short* lWl0 = wlo;
    short* hWr0 = whi + 16384;  short* lWr0 = wlo + 16384;
    short* hWl1 = whi + 32768;  short* lWl1 = wlo + 32768;
    short* hWr1 = whi + 49152;  short* lWr1 = wlo + 49152;
    short* hW2  = whi + 65536;  short* lW2  = wlo + 65536;

    const int aggGrid  = (N * 64 + 255) / 256;   // 12500
    const int gemmGrid = (N + 63) / 64;          // 782

    // layer 0
    agg_bf16<<<aggGrid, 256, 0, stream>>>((const unsigned short*)xb, rowptr, csr, aggb, N);
    sage_mfma<<<gemmGrid, 256, 0, stream>>>(
        aggb, xhi, xlo, hWl0, lWl0, hWr0, lWr0, bl0, h1hi, h1lo, N);
    // layer 1 (h1hi doubles as the gather table: h1 >= 0)
    agg_bf16<<<aggGrid, 256, 0, stream>>>((const unsigned short*)h1hi, rowptr, csr, aggb, N);
    sage_mfma<<<gemmGrid, 256, 0, stream>>>(
        aggb, h1hi, h1lo, hWl1, lWl1, hWr1, lWr1, bl1, h2hi, h2lo, N);
    // layer 2
    gemm80<<<gemmGrid, 256, 0, stream>>>(h2hi, h2lo, hW2, lW2, bl2, ylb, yr40, N);
    agg40_kernel<<<aggGrid, 256, 0, stream>>>((const unsigned short*)ylb, yr40, rowptr, csr, out, N);

    // global mean pool
    pool_kernel<<<N_GRAPHS, 320, 0, stream>>>(out, gstart, gsum);
}